// Round 4
// baseline (174.533 us; speedup 1.0000x reference)
//
#include <hip/hip_runtime.h>

// Detail_loss: loss = 0.25/(98*258*256) * sum_{n,h,w} ( |D[h][w+1]-D[h][w-1]| + |D[h+1][w]-D[h-1][w]| )
// where D[n,h,w] = sum_c (infer - ref)[n,c,h,w], zero outside [0,256)^2.
// (identical per-channel-pair kernels -> channel-sum first; conv linearity ->
// difference first; pad rows/cols contribute 0; scale folds the 0.5 coeff,
// 3 output channels, and the /(98*3*258*256) means.)
//
// R3: same per-wave rolling-window structure as R2, but 4 INDEPENDENT waves per
// 256-thread block (no barriers/LDS). R2's 64-thread blocks hit the per-CU
// workgroup cap (~16) -> only ~16 waves/CU; 256-thread blocks at VGPR=64 allow
// 8 blocks/CU = 32 waves/CU for full latency hiding.

#define W 256
#define NIMG 98
#define CH_STRIDE 65536        // 256*256
#define TH 4
#define NSTRIP 64              // 256 / TH
#define NWAVE (NIMG * NSTRIP)  // 6272 waves total
#define NBLK (NWAVE / 4)       // 1568 blocks of 4 waves
#define SCALE (0.25f / 6472704.0f)   // 0.25/(98*258*256)

__device__ __forceinline__ float4 load_D_row(const float* __restrict__ xb,
                                             const float* __restrict__ yb, int r) {
  float4 d = make_float4(0.f, 0.f, 0.f, 0.f);
  if (r >= 0 && r < 256) {              // wave-uniform
    const int off = r * W;
    #pragma unroll
    for (int c = 0; c < 3; ++c) {
      float4 xv = *(const float4*)(xb + c * CH_STRIDE + off);
      float4 yv = *(const float4*)(yb + c * CH_STRIDE + off);
      d.x += xv.x - yv.x;
      d.y += xv.y - yv.y;
      d.z += xv.z - yv.z;
      d.w += xv.w - yv.w;
    }
  }
  return d;
}

__global__ __launch_bounds__(256) void detail_stage1(
    const float* __restrict__ x, const float* __restrict__ y,
    float* __restrict__ partial) {
  const int lane = threadIdx.x & 63;
  const int wv   = threadIdx.x >> 6;          // 4 independent waves per block
  const int gw   = blockIdx.x * 4 + wv;       // global wave id, 0..6271
  const int n    = gw >> 6;                   // image
  const int strip = gw & 63;
  const int r0    = strip * TH;

  const float* xb = x + (size_t)n * 3 * CH_STRIDE + (lane << 2);
  const float* yb = y + (size_t)n * 3 * CH_STRIDE + (lane << 2);

  float4 Dm = load_D_row(xb, yb, r0 - 1);
  float4 D0 = load_D_row(xb, yb, r0);
  float acc = 0.f;

  #pragma unroll
  for (int i = 0; i < TH; ++i) {
    float4 Dp = load_D_row(xb, yb, r0 + i + 1);   // issues while row i computes
    float left  = __shfl_up(D0.w, 1, 64);         // col 4j-1 from lane-1
    float right = __shfl_down(D0.x, 1, 64);       // col 4j+4 from lane+1
    if (lane == 0)  left  = 0.f;                  // image col -1 zero pad
    if (lane == 63) right = 0.f;                  // image col 256 zero pad
    acc += fabsf(D0.y - left)  + fabsf(D0.z - D0.x)
         + fabsf(D0.w - D0.y)  + fabsf(right - D0.z)
         + fabsf(Dp.x - Dm.x)  + fabsf(Dp.y - Dm.y)
         + fabsf(Dp.z - Dm.z)  + fabsf(Dp.w - Dm.w);
    Dm = D0; D0 = Dp;
  }

  #pragma unroll
  for (int off = 32; off > 0; off >>= 1)
    acc += __shfl_down(acc, off, 64);
  if (lane == 0) partial[gw] = acc;               // per-wave slot, no contention
}

__global__ __launch_bounds__(256) void detail_stage2(
    const float* __restrict__ partial, float* __restrict__ out) {
  float acc = 0.f;
  for (int i = threadIdx.x; i < NWAVE; i += 256) acc += partial[i];
  #pragma unroll
  for (int off = 32; off > 0; off >>= 1)
    acc += __shfl_down(acc, off, 64);
  __shared__ float ws[4];
  if ((threadIdx.x & 63) == 0) ws[threadIdx.x >> 6] = acc;
  __syncthreads();
  if (threadIdx.x == 0) out[0] = (ws[0] + ws[1] + ws[2] + ws[3]) * SCALE;
}

// Fallback single-kernel variant (atomic) in case ws_size is too small.
__global__ __launch_bounds__(256) void detail_stage1_atomic(
    const float* __restrict__ x, const float* __restrict__ y,
    float* __restrict__ out) {
  const int lane = threadIdx.x & 63;
  const int wv   = threadIdx.x >> 6;
  const int gw   = blockIdx.x * 4 + wv;
  const int n    = gw >> 6;
  const int strip = gw & 63;
  const int r0    = strip * TH;
  const float* xb = x + (size_t)n * 3 * CH_STRIDE + (lane << 2);
  const float* yb = y + (size_t)n * 3 * CH_STRIDE + (lane << 2);
  float4 Dm = load_D_row(xb, yb, r0 - 1);
  float4 D0 = load_D_row(xb, yb, r0);
  float acc = 0.f;
  #pragma unroll
  for (int i = 0; i < TH; ++i) {
    float4 Dp = load_D_row(xb, yb, r0 + i + 1);
    float left  = __shfl_up(D0.w, 1, 64);
    float right = __shfl_down(D0.x, 1, 64);
    if (lane == 0)  left  = 0.f;
    if (lane == 63) right = 0.f;
    acc += fabsf(D0.y - left)  + fabsf(D0.z - D0.x)
         + fabsf(D0.w - D0.y)  + fabsf(right - D0.z)
         + fabsf(Dp.x - Dm.x)  + fabsf(Dp.y - Dm.y)
         + fabsf(Dp.z - Dm.z)  + fabsf(Dp.w - Dm.w);
    Dm = D0; D0 = Dp;
  }
  #pragma unroll
  for (int off = 32; off > 0; off >>= 1)
    acc += __shfl_down(acc, off, 64);
  if (lane == 0) atomicAdd(out, acc * SCALE);
}

extern "C" void kernel_launch(void* const* d_in, const int* in_sizes, int n_in,
                              void* d_out, int out_size, void* d_ws, size_t ws_size,
                              hipStream_t stream) {
  const float* infer = (const float*)d_in[0];
  const float* ref   = (const float*)d_in[1];
  float* out = (float*)d_out;

  if (ws_size >= NWAVE * sizeof(float)) {
    float* partial = (float*)d_ws;
    detail_stage1<<<NBLK, 256, 0, stream>>>(infer, ref, partial);
    detail_stage2<<<1, 256, 0, stream>>>(partial, out);
  } else {
    hipMemsetAsync(out, 0, sizeof(float), stream);
    detail_stage1_atomic<<<NBLK, 256, 0, stream>>>(infer, ref, out);
  }
}

// Round 5
// 172.183 us; speedup vs baseline: 1.0136x; 1.0136x over previous
//
#include <hip/hip_runtime.h>

// Detail_loss: loss = 0.25/(98*258*256) * sum_{n,h,w} ( |D[h][w+1]-D[h][w-1]| + |D[h+1][w]-D[h-1][w]| )
// where D[n,h,w] = sum_c (infer - ref)[n,c,h,w], zero outside [0,256)^2.
// (identical per-channel-pair conv kernels -> channel-sum first; conv linearity ->
// difference first; pad rows/cols contribute 0; scale folds the 0.5 coeff, the 3
// output channels, and the /(98*3*258*256) means.)
//
// R4: LDS-tiled strip (TH=8, halo dedup -> 1.25x read amp) with ALL of each
// wave's 12-18 float4 global loads issued into registers BEFORE any combine —
// R0-R3 all plateaued at ~60us because the compiled code only kept ~6 loads in
// flight per wave (latency-bound, both pipes idle). Each of the 10 LDS D-rows
// is produced by exactly one wave (rows wv, wv+4, wv+8) — no LDS atomics, one
// barrier. Phase 2: thread=column, 8 rows, stride-1 LDS (conflict-free).
// Per-block partial -> d_ws; tiny stage-2 reduce. 3136 blocks = 12.25/CU.

#define W 256
#define NIMG 98
#define CH_STRIDE 65536          // 256*256
#define TH 8
#define HALO (TH + 2)            // 10 LDS rows
#define NSTRIP 32                // 256 / TH
#define NBLK (NIMG * NSTRIP)     // 3136
#define SCALE (0.25f / 6472704.0f)   // 0.25/(98*258*256)

__global__ __launch_bounds__(256) void detail_stage1(
    const float* __restrict__ x, const float* __restrict__ y,
    float* __restrict__ partial) {
  __shared__ float D[HALO][W];   // 10 KB

  const int tid   = threadIdx.x;
  const int lane  = tid & 63;
  const int wv    = tid >> 6;
  const int b     = blockIdx.x;
  const int n     = b >> 5;          // image
  const int strip = b & 31;
  const int r0    = strip * TH;

  const float* xb = x + (size_t)n * 3 * CH_STRIDE + (lane << 2);
  const float* yb = y + (size_t)n * 3 * CH_STRIDE + (lane << 2);

  // ---- Phase 1a: wave wv owns LDS rows {wv, wv+4, wv+8} < HALO.
  // Issue ALL loads (up to 18 float4/lane) into registers, no arithmetic between.
  const int nrows = (wv < 2) ? 3 : 2;
  float4 vx[3][3], vy[3][3];         // [owned-row j][channel]
  #pragma unroll
  for (int j = 0; j < 3; ++j) {
    if (j < nrows) {                 // wave-uniform
      const int g  = r0 - 1 + (wv + 4 * j);
      const bool ok = (g >= 0) && (g < 256);   // wave-uniform
      const int off = g * W;
      #pragma unroll
      for (int c = 0; c < 3; ++c) {
        if (ok) {
          vx[j][c] = *(const float4*)(xb + c * CH_STRIDE + off);
          vy[j][c] = *(const float4*)(yb + c * CH_STRIDE + off);
        } else {
          vx[j][c] = make_float4(0.f, 0.f, 0.f, 0.f);
          vy[j][c] = make_float4(0.f, 0.f, 0.f, 0.f);
        }
      }
    }
  }

  // ---- Phase 1b: combine to channel-summed difference rows, store to LDS.
  #pragma unroll
  for (int j = 0; j < 3; ++j) {
    if (j < nrows) {
      const int lr = wv + 4 * j;
      float4 d;
      d.x = (vx[j][0].x - vy[j][0].x) + (vx[j][1].x - vy[j][1].x) + (vx[j][2].x - vy[j][2].x);
      d.y = (vx[j][0].y - vy[j][0].y) + (vx[j][1].y - vy[j][1].y) + (vx[j][2].y - vy[j][2].y);
      d.z = (vx[j][0].z - vy[j][0].z) + (vx[j][1].z - vy[j][1].z) + (vx[j][2].z - vy[j][2].z);
      d.w = (vx[j][0].w - vy[j][0].w) + (vx[j][1].w - vy[j][1].w) + (vx[j][2].w - vy[j][2].w);
      *(float4*)&D[lr][lane << 2] = d;
    }
  }
  __syncthreads();

  // ---- Phase 2: thread = column, walk the 8 strip rows. Stride-1 LDS reads.
  const int w = tid;
  float acc = 0.f;
  #pragma unroll
  for (int r = 0; r < TH; ++r) {
    const float* rp = D[r + 1];
    float left  = (w > 0)     ? rp[w - 1] : 0.f;   // image col -1 zero pad
    float right = (w < W - 1) ? rp[w + 1] : 0.f;   // image col 256 zero pad
    acc += fabsf(right - left) + fabsf(D[r + 2][w] - D[r][w]);
  }

  // ---- Block reduce -> one partial per block (no global atomics).
  #pragma unroll
  for (int off = 32; off > 0; off >>= 1)
    acc += __shfl_down(acc, off, 64);
  __shared__ float ws[4];
  if (lane == 0) ws[wv] = acc;
  __syncthreads();
  if (tid == 0) partial[b] = ws[0] + ws[1] + ws[2] + ws[3];
}

__global__ __launch_bounds__(256) void detail_stage2(
    const float* __restrict__ partial, float* __restrict__ out) {
  float acc = 0.f;
  for (int i = threadIdx.x; i < NBLK; i += 256) acc += partial[i];
  #pragma unroll
  for (int off = 32; off > 0; off >>= 1)
    acc += __shfl_down(acc, off, 64);
  __shared__ float ws[4];
  if ((threadIdx.x & 63) == 0) ws[threadIdx.x >> 6] = acc;
  __syncthreads();
  if (threadIdx.x == 0) out[0] = (ws[0] + ws[1] + ws[2] + ws[3]) * SCALE;
}

// Fallback (atomic) in case ws_size is ever too small for the partial buffer.
__global__ __launch_bounds__(256) void detail_stage1_atomic(
    const float* __restrict__ x, const float* __restrict__ y,
    float* __restrict__ out) {
  __shared__ float D[HALO][W];
  const int tid   = threadIdx.x;
  const int lane  = tid & 63;
  const int wv    = tid >> 6;
  const int b     = blockIdx.x;
  const int n     = b >> 5;
  const int strip = b & 31;
  const int r0    = strip * TH;
  const float* xb = x + (size_t)n * 3 * CH_STRIDE + (lane << 2);
  const float* yb = y + (size_t)n * 3 * CH_STRIDE + (lane << 2);
  const int nrows = (wv < 2) ? 3 : 2;
  float4 vx[3][3], vy[3][3];
  #pragma unroll
  for (int j = 0; j < 3; ++j) {
    if (j < nrows) {
      const int g  = r0 - 1 + (wv + 4 * j);
      const bool ok = (g >= 0) && (g < 256);
      const int off = g * W;
      #pragma unroll
      for (int c = 0; c < 3; ++c) {
        if (ok) {
          vx[j][c] = *(const float4*)(xb + c * CH_STRIDE + off);
          vy[j][c] = *(const float4*)(yb + c * CH_STRIDE + off);
        } else {
          vx[j][c] = make_float4(0.f, 0.f, 0.f, 0.f);
          vy[j][c] = make_float4(0.f, 0.f, 0.f, 0.f);
        }
      }
    }
  }
  #pragma unroll
  for (int j = 0; j < 3; ++j) {
    if (j < nrows) {
      const int lr = wv + 4 * j;
      float4 d;
      d.x = (vx[j][0].x - vy[j][0].x) + (vx[j][1].x - vy[j][1].x) + (vx[j][2].x - vy[j][2].x);
      d.y = (vx[j][0].y - vy[j][0].y) + (vx[j][1].y - vy[j][1].y) + (vx[j][2].y - vy[j][2].y);
      d.z = (vx[j][0].z - vy[j][0].z) + (vx[j][1].z - vy[j][1].z) + (vx[j][2].z - vy[j][2].z);
      d.w = (vx[j][0].w - vy[j][0].w) + (vx[j][1].w - vy[j][1].w) + (vx[j][2].w - vy[j][2].w);
      *(float4*)&D[lr][lane << 2] = d;
    }
  }
  __syncthreads();
  const int w = tid;
  float acc = 0.f;
  #pragma unroll
  for (int r = 0; r < TH; ++r) {
    const float* rp = D[r + 1];
    float left  = (w > 0)     ? rp[w - 1] : 0.f;
    float right = (w < W - 1) ? rp[w + 1] : 0.f;
    acc += fabsf(right - left) + fabsf(D[r + 2][w] - D[r][w]);
  }
  #pragma unroll
  for (int off = 32; off > 0; off >>= 1)
    acc += __shfl_down(acc, off, 64);
  __shared__ float ws[4];
  if (lane == 0) ws[wv] = acc;
  __syncthreads();
  if (tid == 0) atomicAdd(out, (ws[0] + ws[1] + ws[2] + ws[3]) * SCALE);
}

extern "C" void kernel_launch(void* const* d_in, const int* in_sizes, int n_in,
                              void* d_out, int out_size, void* d_ws, size_t ws_size,
                              hipStream_t stream) {
  const float* infer = (const float*)d_in[0];
  const float* ref   = (const float*)d_in[1];
  float* out = (float*)d_out;

  if (ws_size >= NBLK * sizeof(float)) {
    float* partial = (float*)d_ws;
    detail_stage1<<<NBLK, 256, 0, stream>>>(infer, ref, partial);
    detail_stage2<<<1, 256, 0, stream>>>(partial, out);
  } else {
    hipMemsetAsync(out, 0, sizeof(float), stream);
    detail_stage1_atomic<<<NBLK, 256, 0, stream>>>(infer, ref, out);
  }
}

// Round 6
// 167.282 us; speedup vs baseline: 1.0433x; 1.0293x over previous
//
#include <hip/hip_runtime.h>

// Detail_loss: loss = 0.25/(98*258*256) * sum_{n,h,w} ( |D[h][w+1]-D[h][w-1]| + |D[h+1][w]-D[h-1][w]| )
// where D[n,h,w] = sum_c (infer - ref)[n,c,h,w], zero outside [0,256)^2.
// (identical per-channel-pair conv kernels -> channel-sum first; conv linearity ->
// difference first; pad rows/cols contribute 0; scale folds the 0.5 coeff, the 3
// output channels, and the /(98*3*258*256) means.)
//
// R5: R0-R4 all plateaued at ~57-63us because the compiler never keeps more than
// ~6 VGPR-destined loads in flight per wave (latency-bound; VALUBusy<7%, BW ~27%
// of HBM ceiling). Fix: __builtin_amdgcn_global_load_lds — async global->LDS with
// NO VGPR destination, so nothing for the compiler to serialize. Each block issues
// 60 async 1-KB row loads (6 tensor-channel slots x 10 halo rows, 15/wave), then a
// single barrier drain, then computes from LDS. 70 KB LDS -> 2 blocks/CU = 120 KB
// in flight per CU (Little's law needs ~15 KB at 6.3 TB/s) — server-bound, not
// latency-bound. OOB halo rows: load clamped, masked to D=0 in phase 2a.

#define W 256
#define NIMG 98
#define CH_STRIDE 65536          // 256*256
#define TH 8
#define HALO (TH + 2)            // 10 rows incl. halo
#define NSTRIP 32                // 256 / TH
#define NBLK (NIMG * NSTRIP)     // 3136
#define SCALE (0.25f / 6472704.0f)   // 0.25/(98*258*256)

__device__ __forceinline__ void async_copy16(const float* g, float* l) {
  // width=16: one instruction moves 64 lanes x 16 B = 1 KB (one image row).
  // LDS dest = wave-uniform base + lane*16 (hardware), global addr per-lane.
  __builtin_amdgcn_global_load_lds(
      (const __attribute__((address_space(1))) void*)g,
      (__attribute__((address_space(3))) void*)l,
      16, 0, 0);
}

struct SmemT {
  float raw[6][HALO][W];   // 60 KB: slots 0-2 = x ch0-2, 3-5 = y ch0-2
  float Dsh[HALO][W];      // 10 KB: channel-summed difference rows
  float ws[4];
};

__device__ __forceinline__ float block_body(const float* __restrict__ x,
                                            const float* __restrict__ y,
                                            SmemT& sm) {
  const int tid   = threadIdx.x;
  const int lane  = tid & 63;
  const int wv    = tid >> 6;
  const int b     = blockIdx.x;
  const int n     = b >> 5;          // image
  const int strip = b & 31;
  const int r0    = strip * TH;

  const float* xb = x + (size_t)n * 3 * CH_STRIDE;
  const float* yb = y + (size_t)n * 3 * CH_STRIDE;

  // ---- Phase 1: 60 async row loads, 15 per wave, hardware-queued (no VGPRs).
  #pragma unroll
  for (int i = 0; i < 15; ++i) {
    const int id = wv + 4 * i;       // 0..59, wave-uniform
    const int s  = id / HALO;        // tensor-channel slot 0..5
    const int lr = id % HALO;        // local halo row 0..9
    int g = r0 - 1 + lr;
    g = (g < 0) ? 0 : (g > 255 ? 255 : g);   // clamp; OOB masked to 0 in phase 2a
    const float* gp = ((s < 3) ? (xb + s * CH_STRIDE) : (yb + (s - 3) * CH_STRIDE))
                      + g * W + (lane << 2);
    async_copy16(gp, &sm.raw[s][lr][0]);
  }
  __syncthreads();   // single vmcnt drain for all 60 loads

  // ---- Phase 2a: thread = column w; channel-summed difference rows.
  // D kept in registers for the vertical term; also stored to LDS for horizontal.
  const int w = tid;
  float d[HALO];
  #pragma unroll
  for (int lr = 0; lr < HALO; ++lr) {
    const int g = r0 - 1 + lr;       // block-uniform branch
    float v = 0.f;
    if (g >= 0 && g < 256) {
      v = (sm.raw[0][lr][w] - sm.raw[3][lr][w])
        + (sm.raw[1][lr][w] - sm.raw[4][lr][w])
        + (sm.raw[2][lr][w] - sm.raw[5][lr][w]);
    }
    d[lr] = v;
    sm.Dsh[lr][w] = v;
  }
  __syncthreads();

  // ---- Phase 2b: 8 strip rows; horizontal from LDS (stride-1), vertical from regs.
  float acc = 0.f;
  #pragma unroll
  for (int r = 0; r < TH; ++r) {
    const float* rp = sm.Dsh[r + 1];
    float left  = (w > 0)     ? rp[w - 1] : 0.f;   // image col -1 zero pad
    float right = (w < W - 1) ? rp[w + 1] : 0.f;   // image col 256 zero pad
    acc += fabsf(right - left) + fabsf(d[r + 2] - d[r]);
  }

  // ---- Block reduce.
  #pragma unroll
  for (int off = 32; off > 0; off >>= 1)
    acc += __shfl_down(acc, off, 64);
  if (lane == 0) sm.ws[wv] = acc;
  __syncthreads();
  return sm.ws[0] + sm.ws[1] + sm.ws[2] + sm.ws[3];
}

__global__ __launch_bounds__(256) void detail_stage1(
    const float* __restrict__ x, const float* __restrict__ y,
    float* __restrict__ partial) {
  __shared__ SmemT sm;
  float s = block_body(x, y, sm);
  if (threadIdx.x == 0) partial[blockIdx.x] = s;
}

__global__ __launch_bounds__(256) void detail_stage1_atomic(
    const float* __restrict__ x, const float* __restrict__ y,
    float* __restrict__ out) {
  __shared__ SmemT sm;
  float s = block_body(x, y, sm);
  if (threadIdx.x == 0) atomicAdd(out, s * SCALE);
}

__global__ __launch_bounds__(256) void detail_stage2(
    const float* __restrict__ partial, float* __restrict__ out) {
  float acc = 0.f;
  for (int i = threadIdx.x; i < NBLK; i += 256) acc += partial[i];
  #pragma unroll
  for (int off = 32; off > 0; off >>= 1)
    acc += __shfl_down(acc, off, 64);
  __shared__ float ws[4];
  if ((threadIdx.x & 63) == 0) ws[threadIdx.x >> 6] = acc;
  __syncthreads();
  if (threadIdx.x == 0) out[0] = (ws[0] + ws[1] + ws[2] + ws[3]) * SCALE;
}

extern "C" void kernel_launch(void* const* d_in, const int* in_sizes, int n_in,
                              void* d_out, int out_size, void* d_ws, size_t ws_size,
                              hipStream_t stream) {
  const float* infer = (const float*)d_in[0];
  const float* ref   = (const float*)d_in[1];
  float* out = (float*)d_out;

  if (ws_size >= NBLK * sizeof(float)) {
    float* partial = (float*)d_ws;
    detail_stage1<<<NBLK, 256, 0, stream>>>(infer, ref, partial);
    detail_stage2<<<1, 256, 0, stream>>>(partial, out);
  } else {
    hipMemsetAsync(out, 0, sizeof(float), stream);
    detail_stage1_atomic<<<NBLK, 256, 0, stream>>>(infer, ref, out);
  }
}